// Round 10
// baseline (422.959 us; speedup 1.0000x reference)
//
#include <hip/hip_runtime.h>
#include <hip/hip_bf16.h>

constexpr int CH    = 128;   // IN_CH == OUT_CH == 128
constexpr int BSH   = 7;     // 128 nodes per coarse bucket
constexpr int CAPSH = 12;    // 4096 slots per bucket region (max bucket ~2.3k)
constexpr int CHUNK = 6250;  // edges per k_bin block (E=1.6M / 256)
constexpr int CHCAP = 6400;  // LDS capacity for block-local sort

typedef __attribute__((ext_vector_type(8))) short short8v;   // 8 bf16 (4 VGPRs)
typedef __attribute__((ext_vector_type(4))) float f32x4;     // 4 fp32 acc
typedef __attribute__((ext_vector_type(2))) float f32x2;     // packed f32 pair

__device__ __forceinline__ unsigned short f2bf(float f) {
    unsigned u = __float_as_uint(f);
    u = (u + 0x7fffu + ((u >> 16) & 1u)) >> 16;   // RTN-even
    return (unsigned short)u;
}

// ---------- 1. coarse bucket sort via block-local LDS counting sort ----------
__global__ __launch_bounds__(256) void k_bin(const int* __restrict__ src,
                                             const int* __restrict__ dst, int E,
                                             int* __restrict__ bucket_cnt,
                                             unsigned* __restrict__ packed,
                                             const float* __restrict__ W,
                                             unsigned short* __restrict__ Wt) {
    __shared__ int hist[1024];            // per-bucket count (this block)
    __shared__ int start[1024];           // exclusive scan (local)
    __shared__ int cursor[1024];          // scatter cursor (local)
    __shared__ int gofs[1024];            // global base within bucket region
    __shared__ int tscan[256];
    __shared__ unsigned       sorted[CHCAP];
    __shared__ unsigned short sbkt[CHCAP];

    int t = threadIdx.x;
    if (blockIdx.x < 32) {                // W -> Wt bf16 (independent global work)
        int idx = blockIdx.x * 256 + t;   // 8192 entries = pairs of k
        int c  = idx & 127;
        int k2 = (idx >> 7) * 2;
        unsigned pk = (unsigned)f2bf(W[(size_t)k2 * CH + c]) |
                      ((unsigned)f2bf(W[(size_t)(k2 + 1) * CH + c]) << 16);
        *(unsigned*)(Wt + (size_t)c * CH + k2) = pk;
    }
    #pragma unroll
    for (int i = 0; i < 4; ++i) hist[t + i * 256] = 0;
    __syncthreads();

    int e0 = blockIdx.x * CHUNK;
    int e1 = min(e0 + CHUNK, E);
    // phase A: histogram
    for (int e = e0 + t; e < e1; e += 256)
        atomicAdd(&hist[dst[e] >> BSH], 1);
    __syncthreads();
    // phase B: exclusive scan over 1024 bins (4 per thread)
    int b4 = t * 4;
    int c0 = hist[b4], c1 = hist[b4 + 1], c2 = hist[b4 + 2], c3 = hist[b4 + 3];
    int tsum = c0 + c1 + c2 + c3;
    tscan[t] = tsum;
    __syncthreads();
    for (int off = 1; off < 256; off <<= 1) {
        int v = (t >= off) ? tscan[t - off] : 0;
        __syncthreads();
        tscan[t] += v;
        __syncthreads();
    }
    int eb = tscan[t] - tsum;             // exclusive base for this thread's 4 bins
    start[b4]     = eb;
    start[b4 + 1] = eb + c0;
    start[b4 + 2] = eb + c0 + c1;
    start[b4 + 3] = eb + c0 + c1 + c2;
    cursor[b4]     = eb;
    cursor[b4 + 1] = eb + c0;
    cursor[b4 + 2] = eb + c0 + c1;
    cursor[b4 + 3] = eb + c0 + c1 + c2;
    __syncthreads();
    // phase C: reserve global runs (one atomic per non-empty bin)
    #pragma unroll
    for (int i = 0; i < 4; ++i) {
        int b = t + i * 256;
        int c = hist[b];
        gofs[b] = (c > 0) ? atomicAdd(&bucket_cnt[b], c) : 0;
    }
    __syncthreads();
    // phase D: LDS scatter (block-local sort by bucket)
    for (int e = e0 + t; e < e1; e += 256) {
        int d = dst[e];
        int b = d >> BSH;
        int pos = atomicAdd(&cursor[b], 1);
        sorted[pos] = (unsigned)src[e] | ((unsigned)(d & ((1 << BSH) - 1)) << 20);
        sbkt[pos] = (unsigned short)b;
    }
    __syncthreads();
    // phase E: coalesced copy-out
    int nloc = e1 - e0;
    for (int i = t; i < nloc; i += 256) {
        int b = sbkt[i];
        int gpos = (b << CAPSH) + gofs[b] + (i - start[b]);
        packed[gpos] = sorted[i];
    }
}

// ---------- 2. per-bucket fine sort + rowinfo + dinv ----------
__global__ __launch_bounds__(256) void k_bucket(const int* __restrict__ bucket_cnt,
                                                const unsigned* __restrict__ packed,
                                                int* __restrict__ eidx,
                                                uint2* __restrict__ rowinfo,
                                                float* __restrict__ dinv, int N) {
    __shared__ int fh[128];    // fine histogram
    __shared__ int fs[128];    // scan
    __shared__ int fc[128];    // cursor
    int b = blockIdx.x;
    int t = threadIdx.x;
    int cnt = bucket_cnt[b];
    if (t < 128) fh[t] = 0;
    __syncthreads();
    const unsigned* pk = packed + ((size_t)b << CAPSH);
    for (int i = t; i < cnt; i += 256)
        atomicAdd(&fh[(pk[i] >> 20) & 127], 1);
    __syncthreads();
    if (t < 128) fs[t] = fh[t];
    __syncthreads();
    for (int off = 1; off < 128; off <<= 1) {     // Hillis-Steele inclusive scan
        int v = 0;
        if (t < 128 && t >= off) v = fs[t - off];
        __syncthreads();
        if (t < 128) fs[t] += v;
        __syncthreads();
    }
    if (t < 128) {
        int excl = fs[t] - fh[t];
        fc[t] = excl;
        int node = (b << BSH) + t;
        if (node < N) {
            rowinfo[node] = make_uint2((unsigned)((b << CAPSH) + excl), (unsigned)fh[t]);
            dinv[node] = rsqrtf((float)fh[t] + 1.0f);   // +1 self-loop
        }
    }
    __syncthreads();
    int* eo = eidx + ((size_t)b << CAPSH);
    for (int i = t; i < cnt; i += 256) {
        unsigned p = pk[i];
        int f = (p >> 20) & 127;
        int pos = atomicAdd(&fc[f], 1);
        eo[pos] = (int)(p & 0xFFFFF);
    }
}

// ---------- 3. xwb[r] = bf16(dinv[r] * (x @ W)[r])  via MFMA ----------
__global__ __launch_bounds__(256) void k_gemm(const float* __restrict__ x,
                                              const unsigned short* __restrict__ Wt,
                                              const float* __restrict__ dinv,
                                              unsigned short* __restrict__ xwb, int N) {
    __shared__ __align__(16) unsigned short xs[64 * CH];   // epilogue bounce (16 KB)
    int t = threadIdx.x;
    int w = t >> 6, lane = t & 63;
    int c16 = lane & 15, kq = lane >> 4, kb = kq * 8;
    int row0 = blockIdx.x * 64;
    int arow = row0 + w * 16 + c16;
    bool av = arow < N;
    const float* xp = x + (size_t)(av ? arow : 0) * CH;

    f32x4 acc[8];
    #pragma unroll
    for (int f = 0; f < 8; ++f) acc[f] = (f32x4){0.f, 0.f, 0.f, 0.f};

    #pragma unroll
    for (int kc = 0; kc < 4; ++kc) {
        float4 x0 = make_float4(0.f, 0.f, 0.f, 0.f), x1 = x0;
        if (av) {
            x0 = ((const float4*)(xp + kc * 32 + kb))[0];
            x1 = ((const float4*)(xp + kc * 32 + kb))[1];
        }
        union { short8v v; __hip_bfloat162 h[4]; } au;
        au.h[0] = __float22bfloat162_rn(make_float2(x0.x, x0.y));
        au.h[1] = __float22bfloat162_rn(make_float2(x0.z, x0.w));
        au.h[2] = __float22bfloat162_rn(make_float2(x1.x, x1.y));
        au.h[3] = __float22bfloat162_rn(make_float2(x1.z, x1.w));
        #pragma unroll
        for (int f = 0; f < 8; ++f) {
            short8v b = *(const short8v*)(Wt + (size_t)(f * 16 + c16) * CH + kc * 32 + kb);
            acc[f] = __builtin_amdgcn_mfma_f32_16x16x32_bf16(au.v, b, acc[f], 0, 0, 0);
        }
    }

    #pragma unroll
    for (int r = 0; r < 4; ++r) {
        int row_l = w * 16 + kq * 4 + r;            // C/D: row=(lane>>4)*4+reg
        int grow  = row0 + row_l;
        float dv  = (grow < N) ? dinv[grow] : 0.f;
        #pragma unroll
        for (int f = 0; f < 8; ++f) {
            int col = f * 16 + c16;                 // C/D: col=lane&15
            unsigned bo = ((unsigned)((row_l * CH + col) * 2)) ^ ((unsigned)(row_l & 7) << 4);
            *(unsigned short*)((char*)xs + bo) = f2bf(acc[f][r] * dv);
        }
    }
    __syncthreads();
    #pragma unroll
    for (int i = 0; i < 4; ++i) {
        int g = i * 256 + t;            // 1024 granules of 16B
        int row_l = g >> 4;
        unsigned bo = ((unsigned)(g * 16)) ^ ((unsigned)(row_l & 7) << 4);
        uint4 v = *(const uint4*)((const char*)xs + bo);
        int row = row0 + row_l;
        if (row < N) ((uint4*)(xwb + (size_t)row * CH))[g & 15] = v;
    }
}

// ---------- 4. channel-sliced gather: slice s (16 ch, 3.2 MB) pinned to XCD s ----------
// blockIdx & 7 == slice; round-robin block->XCD dispatch makes each XCD re-read
// only its own L2-resident slice of xwb. 2 lanes x dwordx4 per edge per slice.
// All __shfl unconditional (R8 lesson).
#define ACCP(U) \
    acc0 += (f32x2){__uint_as_float((U).x << 16), __uint_as_float((U).x & 0xffff0000u)}; \
    acc1 += (f32x2){__uint_as_float((U).y << 16), __uint_as_float((U).y & 0xffff0000u)}; \
    acc2 += (f32x2){__uint_as_float((U).z << 16), __uint_as_float((U).z & 0xffff0000u)}; \
    acc3 += (f32x2){__uint_as_float((U).w << 16), __uint_as_float((U).w & 0xffff0000u)};

__global__ __launch_bounds__(256) void k_gather(const uint2* __restrict__ rowinfo,
                                                const int* __restrict__ eidx,
                                                const unsigned short* __restrict__ xwb,
                                                const float* __restrict__ dinv,
                                                const float* __restrict__ bias,
                                                float* __restrict__ out, int N) {
    int s    = blockIdx.x & 7;            // slice == XCD (heuristic; perf-only)
    int g    = blockIdx.x >> 3;
    int tid  = threadIdx.x;
    int lane = tid & 63;
    int wv   = tid >> 6;
    int eh   = lane >> 1;                 // edge slot 0..31
    int half = lane & 1;                  // which 8-ch half of the 16-ch slice
    const uint4* xw4 = (const uint4*)xwb;
    int sb = s * 2 + half;                // uint4 index within a 256-B row

    // this lane's 8 channels: c0 = s*16 + half*8
    float4 b0 = ((const float4*)bias)[s * 4 + half * 2];
    float4 b1 = ((const float4*)bias)[s * 4 + half * 2 + 1];

    #pragma unroll
    for (int i = 0; i < 4; ++i) {
        int n = g * 16 + wv * 4 + i;      // wave-uniform
        if (n >= N) break;
        uint2 ri = rowinfo[n];
        int beg = (int)ri.x;
        int deg = (int)ri.y;
        f32x2 acc0 = {0.f, 0.f}, acc1 = {0.f, 0.f}, acc2 = {0.f, 0.f}, acc3 = {0.f, 0.f};
        for (int p0 = 0; p0 < deg; p0 += 64) {
            int m = deg - p0; if (m > 64) m = 64;
            int myi = 0;
            if (lane < m) myi = eidx[beg + p0 + lane];   // coalesced batch load
            for (int j = 0; j < m; j += 32) {            // j in {0,32}
                int e = j + eh;                          // 0..63
                int a = __shfl(myi, e);                  // unconditional, all lanes
                int srow = (e < m) ? a : N;              // OOB -> zero row
                uint4 u = xw4[(size_t)srow * 16 + sb];
                ACCP(u);
            }
        }
        // reduce across the 32 edge slots (lane bits 1..5)
        #pragma unroll
        for (int st = 2; st <= 32; st <<= 1) {
            acc0.x += __shfl_xor(acc0.x, st);  acc0.y += __shfl_xor(acc0.y, st);
            acc1.x += __shfl_xor(acc1.x, st);  acc1.y += __shfl_xor(acc1.y, st);
            acc2.x += __shfl_xor(acc2.x, st);  acc2.y += __shfl_xor(acc2.y, st);
            acc3.x += __shfl_xor(acc3.x, st);  acc3.y += __shfl_xor(acc3.y, st);
        }
        if (eh == 0) {                     // lanes 0 (half 0) and 1 (half 1)
            float dn = dinv[n];
            uint4 u = xw4[(size_t)n * 16 + sb];   // self-loop row (pre-scaled)
            ACCP(u);
            float4 o0, o1;
            o0.x = fmaxf(fmaf(acc0.x, dn, b0.x), 0.f);
            o0.y = fmaxf(fmaf(acc0.y, dn, b0.y), 0.f);
            o0.z = fmaxf(fmaf(acc1.x, dn, b0.z), 0.f);
            o0.w = fmaxf(fmaf(acc1.y, dn, b0.w), 0.f);
            o1.x = fmaxf(fmaf(acc2.x, dn, b1.x), 0.f);
            o1.y = fmaxf(fmaf(acc2.y, dn, b1.y), 0.f);
            o1.z = fmaxf(fmaf(acc3.x, dn, b1.z), 0.f);
            o1.w = fmaxf(fmaf(acc3.y, dn, b1.w), 0.f);
            float* op = out + (size_t)n * CH + s * 16 + half * 8;
            ((float4*)op)[0] = o0;
            ((float4*)op)[1] = o1;
        }
    }
}

extern "C" void kernel_launch(void* const* d_in, const int* in_sizes, int n_in,
                              void* d_out, int out_size, void* d_ws, size_t ws_size,
                              hipStream_t stream) {
    const float* x  = (const float*)d_in[0];
    const int*   ei = (const int*)d_in[1];
    const float* W  = (const float*)d_in[2];
    const float* b  = (const float*)d_in[3];

    int N = in_sizes[0] / CH;
    int E = in_sizes[1] / 2;
    const int* src = ei;
    const int* dst = ei + E;
    float* out = (float*)d_out;

    int nbuck = (N + (1 << BSH) - 1) >> BSH;     // 782
    size_t nslots = (size_t)nbuck << CAPSH;      // 3.2M

    // workspace layout (aligned to 256 B each)
    auto al = [](uintptr_t p) { return (p + 255) & ~(uintptr_t)255; };
    uintptr_t base = (uintptr_t)d_ws;
    unsigned short* xwb = (unsigned short*)base;          // (N+1)*CH bf16, row N = zeros
    int* bucket_cnt = (int*)(xwb + (size_t)(N + 1) * CH); // nbuck (right after zero row)
    uintptr_t p = al((uintptr_t)(bucket_cnt + nbuck));
    uint2* rowinfo  = (uint2*)p;               p = al(p + (size_t)N * 8);
    float* dinv     = (float*)p;               p = al(p + (size_t)N * 4);
    unsigned short* Wt = (unsigned short*)p;   p = al(p + (size_t)CH * CH * 2);
    unsigned* packed   = (unsigned*)p;         p = al(p + nslots * 4);
    int* eidx          = (int*)p;

    int nbin = (E + CHUNK - 1) / CHUNK;          // 256 for E=1.6M

    // one memset: xwb zero row + bucket_cnt (contiguous)
    hipMemsetAsync(xwb + (size_t)N * CH, 0, (size_t)CH * 2 + (size_t)nbuck * 4, stream);
    k_bin   <<<nbin, 256, 0, stream>>>(src, dst, E, bucket_cnt, packed, W, Wt);
    k_bucket<<<nbuck, 256, 0, stream>>>(bucket_cnt, packed, eidx, rowinfo, dinv, N);
    k_gemm  <<<(N + 63) / 64, 256, 0, stream>>>(x, Wt, dinv, xwb, N);
    {
        int ngrp = (N + 15) / 16;                // 16 nodes per block
        k_gather<<<ngrp * 8, 256, 0, stream>>>(rowinfo, eidx, xwb, dinv, b, out, N);
    }
}

// Round 11
// 422.905 us; speedup vs baseline: 1.0001x; 1.0001x over previous
//
#include <hip/hip_runtime.h>
#include <hip/hip_bf16.h>

constexpr int CH    = 128;   // IN_CH == OUT_CH == 128
constexpr int BSH   = 7;     // 128 nodes per coarse bucket
constexpr int CAPSH = 12;    // 4096 slots per bucket region (max bucket ~2.3k)
constexpr int CHUNK = 6250;  // edges per k_bin block (E=1.6M / 256)
constexpr int CHCAP = 6400;  // LDS capacity for block-local sort

typedef __attribute__((ext_vector_type(8))) short short8v;   // 8 bf16 (4 VGPRs)
typedef __attribute__((ext_vector_type(4))) float f32x4;     // 4 fp32 acc
typedef __attribute__((ext_vector_type(2))) float f32x2;     // packed f32 pair

__device__ __forceinline__ unsigned short f2bf(float f) {
    unsigned u = __float_as_uint(f);
    u = (u + 0x7fffu + ((u >> 16) & 1u)) >> 16;   // RTN-even
    return (unsigned short)u;
}

// ---------- 1. coarse bucket sort via block-local LDS counting sort ----------
// blocks 0..31: also convert W -> Wt bf16; block 32: zero the 8 per-slice zero rows
__global__ __launch_bounds__(256) void k_bin(const int* __restrict__ src,
                                             const int* __restrict__ dst, int E, int N,
                                             int* __restrict__ bucket_cnt,
                                             unsigned* __restrict__ packed,
                                             const float* __restrict__ W,
                                             unsigned short* __restrict__ Wt,
                                             unsigned short* __restrict__ xws) {
    __shared__ int hist[1024];            // per-bucket count (this block)
    __shared__ int start[1024];           // exclusive scan (local)
    __shared__ int cursor[1024];          // scatter cursor (local)
    __shared__ int gofs[1024];            // global base within bucket region
    __shared__ int tscan[256];
    __shared__ unsigned       sorted[CHCAP];
    __shared__ unsigned short sbkt[CHCAP];

    int t = threadIdx.x;
    if (blockIdx.x < 32) {                // W -> Wt bf16 (independent global work)
        int idx = blockIdx.x * 256 + t;   // 8192 entries = pairs of k
        int c  = idx & 127;
        int k2 = (idx >> 7) * 2;
        unsigned pk = (unsigned)f2bf(W[(size_t)k2 * CH + c]) |
                      ((unsigned)f2bf(W[(size_t)(k2 + 1) * CH + c]) << 16);
        *(unsigned*)(Wt + (size_t)c * CH + k2) = pk;
    }
    if (blockIdx.x == 32 && t < 128) {    // zero row N of each slice region
        int sl = t >> 4, c = t & 15;
        xws[((size_t)sl * (N + 1) + N) * 16 + c] = 0;
    }
    #pragma unroll
    for (int i = 0; i < 4; ++i) hist[t + i * 256] = 0;
    __syncthreads();

    int e0 = blockIdx.x * CHUNK;
    int e1 = min(e0 + CHUNK, E);
    // phase A: histogram
    for (int e = e0 + t; e < e1; e += 256)
        atomicAdd(&hist[dst[e] >> BSH], 1);
    __syncthreads();
    // phase B: exclusive scan over 1024 bins (4 per thread)
    int b4 = t * 4;
    int c0 = hist[b4], c1 = hist[b4 + 1], c2 = hist[b4 + 2], c3 = hist[b4 + 3];
    int tsum = c0 + c1 + c2 + c3;
    tscan[t] = tsum;
    __syncthreads();
    for (int off = 1; off < 256; off <<= 1) {
        int v = (t >= off) ? tscan[t - off] : 0;
        __syncthreads();
        tscan[t] += v;
        __syncthreads();
    }
    int eb = tscan[t] - tsum;             // exclusive base for this thread's 4 bins
    start[b4]     = eb;
    start[b4 + 1] = eb + c0;
    start[b4 + 2] = eb + c0 + c1;
    start[b4 + 3] = eb + c0 + c1 + c2;
    cursor[b4]     = eb;
    cursor[b4 + 1] = eb + c0;
    cursor[b4 + 2] = eb + c0 + c1;
    cursor[b4 + 3] = eb + c0 + c1 + c2;
    __syncthreads();
    // phase C: reserve global runs (one atomic per non-empty bin)
    #pragma unroll
    for (int i = 0; i < 4; ++i) {
        int b = t + i * 256;
        int c = hist[b];
        gofs[b] = (c > 0) ? atomicAdd(&bucket_cnt[b], c) : 0;
    }
    __syncthreads();
    // phase D: LDS scatter (block-local sort by bucket)
    for (int e = e0 + t; e < e1; e += 256) {
        int d = dst[e];
        int b = d >> BSH;
        int pos = atomicAdd(&cursor[b], 1);
        sorted[pos] = (unsigned)src[e] | ((unsigned)(d & ((1 << BSH) - 1)) << 20);
        sbkt[pos] = (unsigned short)b;
    }
    __syncthreads();
    // phase E: coalesced copy-out
    int nloc = e1 - e0;
    for (int i = t; i < nloc; i += 256) {
        int b = sbkt[i];
        int gpos = (b << CAPSH) + gofs[b] + (i - start[b]);
        packed[gpos] = sorted[i];
    }
}

// ---------- 2. per-bucket fine sort + rowinfo + dinv ----------
__global__ __launch_bounds__(256) void k_bucket(const int* __restrict__ bucket_cnt,
                                                const unsigned* __restrict__ packed,
                                                int* __restrict__ eidx,
                                                uint2* __restrict__ rowinfo,
                                                float* __restrict__ dinv, int N) {
    __shared__ int fh[128];    // fine histogram
    __shared__ int fs[128];    // scan
    __shared__ int fc[128];    // cursor
    int b = blockIdx.x;
    int t = threadIdx.x;
    int cnt = bucket_cnt[b];
    if (t < 128) fh[t] = 0;
    __syncthreads();
    const unsigned* pk = packed + ((size_t)b << CAPSH);
    for (int i = t; i < cnt; i += 256)
        atomicAdd(&fh[(pk[i] >> 20) & 127], 1);
    __syncthreads();
    if (t < 128) fs[t] = fh[t];
    __syncthreads();
    for (int off = 1; off < 128; off <<= 1) {     // Hillis-Steele inclusive scan
        int v = 0;
        if (t < 128 && t >= off) v = fs[t - off];
        __syncthreads();
        if (t < 128) fs[t] += v;
        __syncthreads();
    }
    if (t < 128) {
        int excl = fs[t] - fh[t];
        fc[t] = excl;
        int node = (b << BSH) + t;
        if (node < N) {
            rowinfo[node] = make_uint2((unsigned)((b << CAPSH) + excl), (unsigned)fh[t]);
            dinv[node] = rsqrtf((float)fh[t] + 1.0f);   // +1 self-loop
        }
    }
    __syncthreads();
    int* eo = eidx + ((size_t)b << CAPSH);
    for (int i = t; i < cnt; i += 256) {
        unsigned p = pk[i];
        int f = (p >> 20) & 127;
        int pos = atomicAdd(&fc[f], 1);
        eo[pos] = (int)(p & 0xFFFFF);
    }
}

// ---------- 3. xws[slice][r][16ch] = bf16(dinv[r] * (x @ W)[r])  via MFMA ----------
__global__ __launch_bounds__(256) void k_gemm(const float* __restrict__ x,
                                              const unsigned short* __restrict__ Wt,
                                              const float* __restrict__ dinv,
                                              unsigned short* __restrict__ xws, int N) {
    __shared__ __align__(16) unsigned short xs[64 * CH];   // epilogue bounce (16 KB)
    int t = threadIdx.x;
    int w = t >> 6, lane = t & 63;
    int c16 = lane & 15, kq = lane >> 4, kb = kq * 8;
    int row0 = blockIdx.x * 64;
    int arow = row0 + w * 16 + c16;
    bool av = arow < N;
    const float* xp = x + (size_t)(av ? arow : 0) * CH;

    f32x4 acc[8];
    #pragma unroll
    for (int f = 0; f < 8; ++f) acc[f] = (f32x4){0.f, 0.f, 0.f, 0.f};

    #pragma unroll
    for (int kc = 0; kc < 4; ++kc) {
        float4 x0 = make_float4(0.f, 0.f, 0.f, 0.f), x1 = x0;
        if (av) {
            x0 = ((const float4*)(xp + kc * 32 + kb))[0];
            x1 = ((const float4*)(xp + kc * 32 + kb))[1];
        }
        union { short8v v; __hip_bfloat162 h[4]; } au;
        au.h[0] = __float22bfloat162_rn(make_float2(x0.x, x0.y));
        au.h[1] = __float22bfloat162_rn(make_float2(x0.z, x0.w));
        au.h[2] = __float22bfloat162_rn(make_float2(x1.x, x1.y));
        au.h[3] = __float22bfloat162_rn(make_float2(x1.z, x1.w));
        #pragma unroll
        for (int f = 0; f < 8; ++f) {
            short8v b = *(const short8v*)(Wt + (size_t)(f * 16 + c16) * CH + kc * 32 + kb);
            acc[f] = __builtin_amdgcn_mfma_f32_16x16x32_bf16(au.v, b, acc[f], 0, 0, 0);
        }
    }

    #pragma unroll
    for (int r = 0; r < 4; ++r) {
        int row_l = w * 16 + kq * 4 + r;            // C/D: row=(lane>>4)*4+reg
        int grow  = row0 + row_l;
        float dv  = (grow < N) ? dinv[grow] : 0.f;
        #pragma unroll
        for (int f = 0; f < 8; ++f) {
            int col = f * 16 + c16;                 // C/D: col=lane&15
            unsigned bo = ((unsigned)((row_l * CH + col) * 2)) ^ ((unsigned)(row_l & 7) << 4);
            *(unsigned short*)((char*)xs + bo) = f2bf(acc[f][r] * dv);
        }
    }
    __syncthreads();
    // write-out: granule g covers row_l = g>>4, slice = (g&15)>>1, half = g&1
    #pragma unroll
    for (int i = 0; i < 4; ++i) {
        int g = i * 256 + t;            // 1024 granules of 16B
        int row_l = g >> 4;
        int sl    = (g >> 1) & 7;
        int hf    = g & 1;
        unsigned bo = ((unsigned)(g * 16)) ^ ((unsigned)(row_l & 7) << 4);
        uint4 v = *(const uint4*)((const char*)xs + bo);
        int row = row0 + row_l;
        if (row < N)
            ((uint4*)xws)[(size_t)(sl * (N + 1) + row) * 2 + hf] = v;
    }
}

// ---------- 4. channel-sliced gather, slice-major layout (slice s -> XCD s) ----------
// slice region = (N+1) rows x 32 B contiguous (3.2 MB, fits 4 MiB XCD L2).
// All __shfl unconditional (R8 lesson).
#define ACCP(U) \
    acc0 += (f32x2){__uint_as_float((U).x << 16), __uint_as_float((U).x & 0xffff0000u)}; \
    acc1 += (f32x2){__uint_as_float((U).y << 16), __uint_as_float((U).y & 0xffff0000u)}; \
    acc2 += (f32x2){__uint_as_float((U).z << 16), __uint_as_float((U).z & 0xffff0000u)}; \
    acc3 += (f32x2){__uint_as_float((U).w << 16), __uint_as_float((U).w & 0xffff0000u)};

__global__ __launch_bounds__(256) void k_gather(const uint2* __restrict__ rowinfo,
                                                const int* __restrict__ eidx,
                                                const unsigned short* __restrict__ xws,
                                                const float* __restrict__ dinv,
                                                const float* __restrict__ bias,
                                                float* __restrict__ out, int N) {
    int s    = blockIdx.x & 7;            // slice == XCD (round-robin heuristic)
    int g    = blockIdx.x >> 3;
    int tid  = threadIdx.x;
    int lane = tid & 63;
    int wv   = tid >> 6;
    int eh   = lane >> 1;                 // edge slot 0..31
    int half = lane & 1;                  // which 8-ch half of the 16-ch slice
    const uint4* xw4 = (const uint4*)xws;
    size_t sbase = (size_t)s * (N + 1);   // block-uniform slice base (rows)

    float4 b0 = ((const float4*)bias)[s * 4 + half * 2];
    float4 b1 = ((const float4*)bias)[s * 4 + half * 2 + 1];

    #pragma unroll
    for (int i = 0; i < 4; ++i) {
        int n = g * 16 + wv * 4 + i;      // wave-uniform
        if (n >= N) break;
        uint2 ri = rowinfo[n];
        int beg = (int)ri.x;
        int deg = (int)ri.y;
        f32x2 acc0 = {0.f, 0.f}, acc1 = {0.f, 0.f}, acc2 = {0.f, 0.f}, acc3 = {0.f, 0.f};
        for (int p0 = 0; p0 < deg; p0 += 64) {
            int m = deg - p0; if (m > 64) m = 64;
            int myi = 0;
            if (lane < m) myi = eidx[beg + p0 + lane];   // coalesced batch load
            for (int j = 0; j < m; j += 32) {            // j in {0,32}
                int e = j + eh;                          // 0..63
                int a = __shfl(myi, e);                  // unconditional, all lanes
                int srow = (e < m) ? a : N;              // OOB -> per-slice zero row
                uint4 u = xw4[(sbase + srow) * 2 + half];
                ACCP(u);
            }
        }
        // reduce across the 32 edge slots (lane bits 1..5)
        #pragma unroll
        for (int st = 2; st <= 32; st <<= 1) {
            acc0.x += __shfl_xor(acc0.x, st);  acc0.y += __shfl_xor(acc0.y, st);
            acc1.x += __shfl_xor(acc1.x, st);  acc1.y += __shfl_xor(acc1.y, st);
            acc2.x += __shfl_xor(acc2.x, st);  acc2.y += __shfl_xor(acc2.y, st);
            acc3.x += __shfl_xor(acc3.x, st);  acc3.y += __shfl_xor(acc3.y, st);
        }
        if (eh == 0) {                     // lanes 0 (half 0) and 1 (half 1)
            float dn = dinv[n];
            uint4 u = xw4[(sbase + n) * 2 + half];   // self-loop row (pre-scaled)
            ACCP(u);
            float4 o0, o1;
            o0.x = fmaxf(fmaf(acc0.x, dn, b0.x), 0.f);
            o0.y = fmaxf(fmaf(acc0.y, dn, b0.y), 0.f);
            o0.z = fmaxf(fmaf(acc1.x, dn, b0.z), 0.f);
            o0.w = fmaxf(fmaf(acc1.y, dn, b0.w), 0.f);
            o1.x = fmaxf(fmaf(acc2.x, dn, b1.x), 0.f);
            o1.y = fmaxf(fmaf(acc2.y, dn, b1.y), 0.f);
            o1.z = fmaxf(fmaf(acc3.x, dn, b1.z), 0.f);
            o1.w = fmaxf(fmaf(acc3.y, dn, b1.w), 0.f);
            float* op = out + (size_t)n * CH + s * 16 + half * 8;
            ((float4*)op)[0] = o0;
            ((float4*)op)[1] = o1;
        }
    }
}

extern "C" void kernel_launch(void* const* d_in, const int* in_sizes, int n_in,
                              void* d_out, int out_size, void* d_ws, size_t ws_size,
                              hipStream_t stream) {
    const float* x  = (const float*)d_in[0];
    const int*   ei = (const int*)d_in[1];
    const float* W  = (const float*)d_in[2];
    const float* b  = (const float*)d_in[3];

    int N = in_sizes[0] / CH;
    int E = in_sizes[1] / 2;
    const int* src = ei;
    const int* dst = ei + E;
    float* out = (float*)d_out;

    int nbuck = (N + (1 << BSH) - 1) >> BSH;     // 782
    size_t nslots = (size_t)nbuck << CAPSH;      // 3.2M

    // workspace layout (aligned to 256 B each)
    auto al = [](uintptr_t p) { return (p + 255) & ~(uintptr_t)255; };
    uintptr_t base = (uintptr_t)d_ws;
    unsigned short* xws = (unsigned short*)base;          // 8 slices x (N+1) x 16 bf16
    int* bucket_cnt = (int*)(xws + (size_t)(N + 1) * CH);
    uintptr_t p = al((uintptr_t)(bucket_cnt + nbuck));
    uint2* rowinfo  = (uint2*)p;               p = al(p + (size_t)N * 8);
    float* dinv     = (float*)p;               p = al(p + (size_t)N * 4);
    unsigned short* Wt = (unsigned short*)p;   p = al(p + (size_t)CH * CH * 2);
    unsigned* packed   = (unsigned*)p;         p = al(p + nslots * 4);
    int* eidx          = (int*)p;

    int nbin = (E + CHUNK - 1) / CHUNK;          // 256 for E=1.6M

    hipMemsetAsync(bucket_cnt, 0, (size_t)nbuck * 4, stream);
    k_bin   <<<nbin, 256, 0, stream>>>(src, dst, E, N, bucket_cnt, packed, W, Wt, xws);
    k_bucket<<<nbuck, 256, 0, stream>>>(bucket_cnt, packed, eidx, rowinfo, dinv, N);
    k_gemm  <<<(N + 63) / 64, 256, 0, stream>>>(x, Wt, dinv, xws, N);
    {
        int ngrp = (N + 15) / 16;                // 16 nodes per block
        k_gather<<<ngrp * 8, 256, 0, stream>>>(rowinfo, eidx, xws, dinv, b, out, N);
    }
}

// Round 12
// 154.022 us; speedup vs baseline: 2.7461x; 2.7457x over previous
//
#include <hip/hip_runtime.h>
#include <hip/hip_bf16.h>

constexpr int CH    = 128;   // IN_CH == OUT_CH == 128
constexpr int BSH   = 7;     // 128 nodes per coarse bucket
constexpr int CAPSH = 12;    // 4096 slots per bucket region (max bucket ~2.3k)
constexpr int CHUNK = 3125;  // edges per k_bin block (E=1.6M / 512)
constexpr int CHCAP = 3200;  // LDS capacity for block-local sort

typedef __attribute__((ext_vector_type(8))) short short8v;   // 8 bf16 (4 VGPRs)
typedef __attribute__((ext_vector_type(4))) float f32x4;     // 4 fp32 acc

__device__ __forceinline__ unsigned short f2bf(float f) {
    unsigned u = __float_as_uint(f);
    u = (u + 0x7fffu + ((u >> 16) & 1u)) >> 16;   // RTN-even
    return (unsigned short)u;
}

// ---------- 1. coarse bucket sort via block-local LDS counting sort ----------
// 512 blocks (4 resident/CU) for TLP on the serial scan/sort phases.
__global__ __launch_bounds__(256) void k_bin(const int* __restrict__ src,
                                             const int* __restrict__ dst, int E,
                                             int* __restrict__ bucket_cnt,
                                             unsigned* __restrict__ packed,
                                             const float* __restrict__ W,
                                             unsigned short* __restrict__ Wt) {
    __shared__ int hist[1024];            // per-bucket count (this block)
    __shared__ int start[1024];           // exclusive scan (local)
    __shared__ int cursor[1024];          // scatter cursor (local)
    __shared__ int gofs[1024];            // global base within bucket region
    __shared__ int tscan[256];
    __shared__ unsigned       sorted[CHCAP];
    __shared__ unsigned short sbkt[CHCAP];

    int t = threadIdx.x;
    if (blockIdx.x < 32) {                // W -> Wt bf16 (independent global work)
        int idx = blockIdx.x * 256 + t;   // 8192 entries = pairs of k
        int c  = idx & 127;
        int k2 = (idx >> 7) * 2;
        unsigned pk = (unsigned)f2bf(W[(size_t)k2 * CH + c]) |
                      ((unsigned)f2bf(W[(size_t)(k2 + 1) * CH + c]) << 16);
        *(unsigned*)(Wt + (size_t)c * CH + k2) = pk;
    }
    #pragma unroll
    for (int i = 0; i < 4; ++i) hist[t + i * 256] = 0;
    __syncthreads();

    int e0 = blockIdx.x * CHUNK;
    int e1 = min(e0 + CHUNK, E);
    // phase A: histogram
    for (int e = e0 + t; e < e1; e += 256)
        atomicAdd(&hist[dst[e] >> BSH], 1);
    __syncthreads();
    // phase B: exclusive scan over 1024 bins (4 per thread)
    int b4 = t * 4;
    int c0 = hist[b4], c1 = hist[b4 + 1], c2 = hist[b4 + 2], c3 = hist[b4 + 3];
    int tsum = c0 + c1 + c2 + c3;
    tscan[t] = tsum;
    __syncthreads();
    for (int off = 1; off < 256; off <<= 1) {
        int v = (t >= off) ? tscan[t - off] : 0;
        __syncthreads();
        tscan[t] += v;
        __syncthreads();
    }
    int eb = tscan[t] - tsum;             // exclusive base for this thread's 4 bins
    start[b4]     = eb;
    start[b4 + 1] = eb + c0;
    start[b4 + 2] = eb + c0 + c1;
    start[b4 + 3] = eb + c0 + c1 + c2;
    cursor[b4]     = eb;
    cursor[b4 + 1] = eb + c0;
    cursor[b4 + 2] = eb + c0 + c1;
    cursor[b4 + 3] = eb + c0 + c1 + c2;
    __syncthreads();
    // phase C: reserve global runs (one atomic per non-empty bin)
    #pragma unroll
    for (int i = 0; i < 4; ++i) {
        int b = t + i * 256;
        int c = hist[b];
        gofs[b] = (c > 0) ? atomicAdd(&bucket_cnt[b], c) : 0;
    }
    __syncthreads();
    // phase D: LDS scatter (block-local sort by bucket)
    for (int e = e0 + t; e < e1; e += 256) {
        int d = dst[e];
        int b = d >> BSH;
        int pos = atomicAdd(&cursor[b], 1);
        sorted[pos] = (unsigned)src[e] | ((unsigned)(d & ((1 << BSH) - 1)) << 20);
        sbkt[pos] = (unsigned short)b;
    }
    __syncthreads();
    // phase E: coalesced copy-out
    int nloc = e1 - e0;
    for (int i = t; i < nloc; i += 256) {
        int b = sbkt[i];
        int gpos = (b << CAPSH) + gofs[b] + (i - start[b]);
        packed[gpos] = sorted[i];
    }
}

// ---------- 2. per-bucket fine sort + rowinfo + dinv ----------
__global__ __launch_bounds__(256) void k_bucket(const int* __restrict__ bucket_cnt,
                                                const unsigned* __restrict__ packed,
                                                int* __restrict__ eidx,
                                                uint2* __restrict__ rowinfo,
                                                float* __restrict__ dinv, int N) {
    __shared__ int fh[128];    // fine histogram
    __shared__ int fs[128];    // scan
    __shared__ int fc[128];    // cursor
    int b = blockIdx.x;
    int t = threadIdx.x;
    int cnt = bucket_cnt[b];
    if (t < 128) fh[t] = 0;
    __syncthreads();
    const unsigned* pk = packed + ((size_t)b << CAPSH);
    for (int i = t; i < cnt; i += 256)
        atomicAdd(&fh[(pk[i] >> 20) & 127], 1);
    __syncthreads();
    if (t < 128) fs[t] = fh[t];
    __syncthreads();
    for (int off = 1; off < 128; off <<= 1) {     // Hillis-Steele inclusive scan
        int v = 0;
        if (t < 128 && t >= off) v = fs[t - off];
        __syncthreads();
        if (t < 128) fs[t] += v;
        __syncthreads();
    }
    if (t < 128) {
        int excl = fs[t] - fh[t];
        fc[t] = excl;
        int node = (b << BSH) + t;
        if (node < N) {
            rowinfo[node] = make_uint2((unsigned)((b << CAPSH) + excl), (unsigned)fh[t]);
            dinv[node] = rsqrtf((float)fh[t] + 1.0f);   // +1 self-loop
        }
    }
    __syncthreads();
    int* eo = eidx + ((size_t)b << CAPSH);
    for (int i = t; i < cnt; i += 256) {
        unsigned p = pk[i];
        int f = (p >> 20) & 127;
        int pos = atomicAdd(&fc[f], 1);
        eo[pos] = (int)(p & 0xFFFFF);
    }
}

// ---------- 3. xwb[r] = bf16(dinv[r] * (x @ W)[r])  via MFMA ----------
__global__ __launch_bounds__(256) void k_gemm(const float* __restrict__ x,
                                              const unsigned short* __restrict__ Wt,
                                              const float* __restrict__ dinv,
                                              unsigned short* __restrict__ xwb, int N) {
    __shared__ __align__(16) unsigned short xs[64 * CH];   // epilogue bounce (16 KB)
    int t = threadIdx.x;
    int w = t >> 6, lane = t & 63;
    int c16 = lane & 15, kq = lane >> 4, kb = kq * 8;
    int row0 = blockIdx.x * 64;
    int arow = row0 + w * 16 + c16;
    bool av = arow < N;
    const float* xp = x + (size_t)(av ? arow : 0) * CH;

    f32x4 acc[8];
    #pragma unroll
    for (int f = 0; f < 8; ++f) acc[f] = (f32x4){0.f, 0.f, 0.f, 0.f};

    #pragma unroll
    for (int kc = 0; kc < 4; ++kc) {
        float4 x0 = make_float4(0.f, 0.f, 0.f, 0.f), x1 = x0;
        if (av) {
            x0 = ((const float4*)(xp + kc * 32 + kb))[0];
            x1 = ((const float4*)(xp + kc * 32 + kb))[1];
        }
        union { short8v v; __hip_bfloat162 h[4]; } au;
        au.h[0] = __float22bfloat162_rn(make_float2(x0.x, x0.y));
        au.h[1] = __float22bfloat162_rn(make_float2(x0.z, x0.w));
        au.h[2] = __float22bfloat162_rn(make_float2(x1.x, x1.y));
        au.h[3] = __float22bfloat162_rn(make_float2(x1.z, x1.w));
        #pragma unroll
        for (int f = 0; f < 8; ++f) {
            short8v b = *(const short8v*)(Wt + (size_t)(f * 16 + c16) * CH + kc * 32 + kb);
            acc[f] = __builtin_amdgcn_mfma_f32_16x16x32_bf16(au.v, b, acc[f], 0, 0, 0);
        }
    }

    #pragma unroll
    for (int r = 0; r < 4; ++r) {
        int row_l = w * 16 + kq * 4 + r;            // C/D: row=(lane>>4)*4+reg
        int grow  = row0 + row_l;
        float dv  = (grow < N) ? dinv[grow] : 0.f;
        #pragma unroll
        for (int f = 0; f < 8; ++f) {
            int col = f * 16 + c16;                 // C/D: col=lane&15
            unsigned bo = ((unsigned)((row_l * CH + col) * 2)) ^ ((unsigned)(row_l & 7) << 4);
            *(unsigned short*)((char*)xs + bo) = f2bf(acc[f][r] * dv);
        }
    }
    __syncthreads();
    #pragma unroll
    for (int i = 0; i < 4; ++i) {
        int g = i * 256 + t;            // 1024 granules of 16B
        int row_l = g >> 4;
        unsigned bo = ((unsigned)(g * 16)) ^ ((unsigned)(row_l & 7) << 4);
        uint4 v = *(const uint4*)((const char*)xs + bo);
        int row = row0 + row_l;
        if (row < N) ((uint4*)(xwb + (size_t)row * CH))[g & 15] = v;
    }
}

// ---------- 4. fused gather: row-sum, 4 edges/group, 1-deep pipeline (R7 best) ----------
#define ACC8(U) \
    acc[0] += __uint_as_float((U).x << 16); \
    acc[1] += __uint_as_float((U).x & 0xffff0000u); \
    acc[2] += __uint_as_float((U).y << 16); \
    acc[3] += __uint_as_float((U).y & 0xffff0000u); \
    acc[4] += __uint_as_float((U).z << 16); \
    acc[5] += __uint_as_float((U).z & 0xffff0000u); \
    acc[6] += __uint_as_float((U).w << 16); \
    acc[7] += __uint_as_float((U).w & 0xffff0000u);

__global__ __launch_bounds__(256) void k_gather(const uint2* __restrict__ rowinfo,
                                                const int* __restrict__ eidx,
                                                const unsigned short* __restrict__ xwb,
                                                const float* __restrict__ dinv,
                                                const float* __restrict__ bias,
                                                float* __restrict__ out, int N) {
    int n = blockIdx.x * 4 + (threadIdx.x >> 6);
    if (n >= N) return;
    int lane = threadIdx.x & 63;
    int q    = lane >> 4;
    int c16  = lane & 15;
    uint2 ri = rowinfo[n];
    int beg = (int)ri.x;
    int deg = (int)ri.y;
    float acc[8];
    #pragma unroll
    for (int i = 0; i < 8; ++i) acc[i] = 0.f;

    const uint4* xw4 = (const uint4*)xwb;
    for (int p0 = 0; p0 < deg; p0 += 64) {
        int m = deg - p0; if (m > 64) m = 64;
        int myi = 0;
        if (lane < m) myi = eidx[beg + p0 + lane];  // coalesced batch load
        // software pipeline: 1-group lookahead; shfl UNCONDITIONAL (R8 lesson)
        int jj = q;
        int a  = __shfl(myi, jj);
        int s  = (jj < m) ? a : N;
        uint4 u = xw4[(size_t)s * 16 + c16];
        for (int j = 4; j < m; j += 4) {
            int jj2 = j + q;
            int ss  = __shfl(myi, jj2 & 63);        // unconditional
            int s2  = (jj2 < m) ? ss : N;
            uint4 u2 = xw4[(size_t)s2 * 16 + c16];
            ACC8(u);
            u = u2;
        }
        ACC8(u);
    }
    #pragma unroll
    for (int i = 0; i < 8; ++i) {
        acc[i] += __shfl_xor(acc[i], 16);
        acc[i] += __shfl_xor(acc[i], 32);
    }
    if (lane < 16) {
        float dn = dinv[n];
        uint4 u = xw4[(size_t)n * 16 + c16];        // self-loop (pre-scaled)
        ACC8(u);
        float4 b0 = ((const float4*)bias)[c16 * 2];
        float4 b1 = ((const float4*)bias)[c16 * 2 + 1];
        float4 o0, o1;
        o0.x = fmaxf(fmaf(acc[0], dn, b0.x), 0.f);
        o0.y = fmaxf(fmaf(acc[1], dn, b0.y), 0.f);
        o0.z = fmaxf(fmaf(acc[2], dn, b0.z), 0.f);
        o0.w = fmaxf(fmaf(acc[3], dn, b0.w), 0.f);
        o1.x = fmaxf(fmaf(acc[4], dn, b1.x), 0.f);
        o1.y = fmaxf(fmaf(acc[5], dn, b1.y), 0.f);
        o1.z = fmaxf(fmaf(acc[6], dn, b1.z), 0.f);
        o1.w = fmaxf(fmaf(acc[7], dn, b1.w), 0.f);
        ((float4*)(out + (size_t)n * CH))[c16 * 2]     = o0;
        ((float4*)(out + (size_t)n * CH))[c16 * 2 + 1] = o1;
    }
}

extern "C" void kernel_launch(void* const* d_in, const int* in_sizes, int n_in,
                              void* d_out, int out_size, void* d_ws, size_t ws_size,
                              hipStream_t stream) {
    const float* x  = (const float*)d_in[0];
    const int*   ei = (const int*)d_in[1];
    const float* W  = (const float*)d_in[2];
    const float* b  = (const float*)d_in[3];

    int N = in_sizes[0] / CH;
    int E = in_sizes[1] / 2;
    const int* src = ei;
    const int* dst = ei + E;
    float* out = (float*)d_out;

    int nbuck = (N + (1 << BSH) - 1) >> BSH;     // 782
    size_t nslots = (size_t)nbuck << CAPSH;      // 3.2M

    // workspace layout (aligned to 256 B each)
    auto al = [](uintptr_t p) { return (p + 255) & ~(uintptr_t)255; };
    uintptr_t base = (uintptr_t)d_ws;
    unsigned short* xwb = (unsigned short*)base;          // (N+1)*CH bf16, row N = zeros
    int* bucket_cnt = (int*)(xwb + (size_t)(N + 1) * CH); // nbuck (right after zero row)
    uintptr_t p = al((uintptr_t)(bucket_cnt + nbuck));
    uint2* rowinfo  = (uint2*)p;               p = al(p + (size_t)N * 8);
    float* dinv     = (float*)p;               p = al(p + (size_t)N * 4);
    unsigned short* Wt = (unsigned short*)p;   p = al(p + (size_t)CH * CH * 2);
    unsigned* packed   = (unsigned*)p;         p = al(p + nslots * 4);
    int* eidx          = (int*)p;

    int nbin = (E + CHUNK - 1) / CHUNK;          // 512 for E=1.6M

    // one memset: xwb zero row + bucket_cnt (contiguous)
    hipMemsetAsync(xwb + (size_t)N * CH, 0, (size_t)CH * 2 + (size_t)nbuck * 4, stream);
    k_bin   <<<nbin, 256, 0, stream>>>(src, dst, E, bucket_cnt, packed, W, Wt);
    k_bucket<<<nbuck, 256, 0, stream>>>(bucket_cnt, packed, eidx, rowinfo, dinv, N);
    k_gemm  <<<(N + 63) / 64, 256, 0, stream>>>(x, Wt, dinv, xwb, N);
    k_gather<<<(N + 3) / 4, 256, 0, stream>>>(rowinfo, eidx, xwb, dinv, b, out, N);
}

// Round 13
// 149.775 us; speedup vs baseline: 2.8240x; 1.0284x over previous
//
#include <hip/hip_runtime.h>
#include <hip/hip_bf16.h>

constexpr int CH    = 128;   // IN_CH == OUT_CH == 128
constexpr int BSH   = 7;     // 128 nodes per coarse bucket
constexpr int CAPSH = 12;    // 4096 slots per bucket region
constexpr int CHUNK = 3125;  // edges per k_bin block (E=1.6M / 512)
constexpr int CHCAP = 3200;  // LDS capacity for block-local sort
constexpr int BKCAP = 2816;  // LDS cap per bucket in fused gather (mean 2046, sd 45 -> 17 sigma)

typedef __attribute__((ext_vector_type(8))) short short8v;   // 8 bf16 (4 VGPRs)
typedef __attribute__((ext_vector_type(4))) float f32x4;     // 4 fp32 acc

__device__ __forceinline__ unsigned short f2bf(float f) {
    unsigned u = __float_as_uint(f);
    u = (u + 0x7fffu + ((u >> 16) & 1u)) >> 16;   // RTN-even
    return (unsigned short)u;
}

// ---------- 1. coarse bucket sort via block-local LDS counting sort ----------
__global__ __launch_bounds__(256) void k_bin(const int* __restrict__ src,
                                             const int* __restrict__ dst, int E,
                                             int* __restrict__ bucket_cnt,
                                             unsigned* __restrict__ packed,
                                             const float* __restrict__ W,
                                             unsigned short* __restrict__ Wt) {
    __shared__ int hist[1024];            // per-bucket count (this block)
    __shared__ int start[1024];           // exclusive scan (local)
    __shared__ int cursor[1024];          // scatter cursor (local)
    __shared__ int gofs[1024];            // global base within bucket region
    __shared__ int tscan[256];
    __shared__ unsigned       sorted[CHCAP];
    __shared__ unsigned short sbkt[CHCAP];

    int t = threadIdx.x;
    if (blockIdx.x < 32) {                // W -> Wt bf16 (independent global work)
        int idx = blockIdx.x * 256 + t;   // 8192 entries = pairs of k
        int c  = idx & 127;
        int k2 = (idx >> 7) * 2;
        unsigned pk = (unsigned)f2bf(W[(size_t)k2 * CH + c]) |
                      ((unsigned)f2bf(W[(size_t)(k2 + 1) * CH + c]) << 16);
        *(unsigned*)(Wt + (size_t)c * CH + k2) = pk;
    }
    #pragma unroll
    for (int i = 0; i < 4; ++i) hist[t + i * 256] = 0;
    __syncthreads();

    int e0 = blockIdx.x * CHUNK;
    int e1 = min(e0 + CHUNK, E);
    // phase A: histogram
    for (int e = e0 + t; e < e1; e += 256)
        atomicAdd(&hist[dst[e] >> BSH], 1);
    __syncthreads();
    // phase B: exclusive scan over 1024 bins (4 per thread)
    int b4 = t * 4;
    int c0 = hist[b4], c1 = hist[b4 + 1], c2 = hist[b4 + 2], c3 = hist[b4 + 3];
    int tsum = c0 + c1 + c2 + c3;
    tscan[t] = tsum;
    __syncthreads();
    for (int off = 1; off < 256; off <<= 1) {
        int v = (t >= off) ? tscan[t - off] : 0;
        __syncthreads();
        tscan[t] += v;
        __syncthreads();
    }
    int eb = tscan[t] - tsum;             // exclusive base for this thread's 4 bins
    start[b4]     = eb;
    start[b4 + 1] = eb + c0;
    start[b4 + 2] = eb + c0 + c1;
    start[b4 + 3] = eb + c0 + c1 + c2;
    cursor[b4]     = eb;
    cursor[b4 + 1] = eb + c0;
    cursor[b4 + 2] = eb + c0 + c1;
    cursor[b4 + 3] = eb + c0 + c1 + c2;
    __syncthreads();
    // phase C: reserve global runs (one atomic per non-empty bin)
    #pragma unroll
    for (int i = 0; i < 4; ++i) {
        int b = t + i * 256;
        int c = hist[b];
        gofs[b] = (c > 0) ? atomicAdd(&bucket_cnt[b], c) : 0;
    }
    __syncthreads();
    // phase D: LDS scatter (block-local sort by bucket)
    for (int e = e0 + t; e < e1; e += 256) {
        int d = dst[e];
        int b = d >> BSH;
        int pos = atomicAdd(&cursor[b], 1);
        sorted[pos] = (unsigned)src[e] | ((unsigned)(d & ((1 << BSH) - 1)) << 20);
        sbkt[pos] = (unsigned short)b;
    }
    __syncthreads();
    // phase E: coalesced copy-out
    int nloc = e1 - e0;
    for (int i = t; i < nloc; i += 256) {
        int b = sbkt[i];
        int gpos = (b << CAPSH) + gofs[b] + (i - start[b]);
        packed[gpos] = sorted[i];
    }
}

// ---------- 2. per-bucket degree -> dinv (fine sort moved into gather) ----------
__global__ __launch_bounds__(256) void k_deg(const int* __restrict__ bucket_cnt,
                                             const unsigned* __restrict__ packed,
                                             float* __restrict__ dinv, int N) {
    __shared__ int fh[128];
    int b = blockIdx.x;
    int t = threadIdx.x;
    int cnt = bucket_cnt[b];
    if (t < 128) fh[t] = 0;
    __syncthreads();
    const unsigned* pk = packed + ((size_t)b << CAPSH);
    for (int i = t; i < cnt; i += 256)
        atomicAdd(&fh[(pk[i] >> 20) & 127], 1);
    __syncthreads();
    if (t < 128) {
        int node = (b << BSH) + t;
        if (node < N) dinv[node] = rsqrtf((float)fh[t] + 1.0f);   // +1 self-loop
    }
}

// ---------- 3. xwb[r] = bf16(dinv[r] * (x @ W)[r])  via MFMA ----------
__global__ __launch_bounds__(256) void k_gemm(const float* __restrict__ x,
                                              const unsigned short* __restrict__ Wt,
                                              const float* __restrict__ dinv,
                                              unsigned short* __restrict__ xwb, int N) {
    __shared__ __align__(16) unsigned short xs[64 * CH];   // epilogue bounce (16 KB)
    int t = threadIdx.x;
    int w = t >> 6, lane = t & 63;
    int c16 = lane & 15, kq = lane >> 4, kb = kq * 8;
    int row0 = blockIdx.x * 64;
    int arow = row0 + w * 16 + c16;
    bool av = arow < N;
    const float* xp = x + (size_t)(av ? arow : 0) * CH;

    f32x4 acc[8];
    #pragma unroll
    for (int f = 0; f < 8; ++f) acc[f] = (f32x4){0.f, 0.f, 0.f, 0.f};

    #pragma unroll
    for (int kc = 0; kc < 4; ++kc) {
        float4 x0 = make_float4(0.f, 0.f, 0.f, 0.f), x1 = x0;
        if (av) {
            x0 = ((const float4*)(xp + kc * 32 + kb))[0];
            x1 = ((const float4*)(xp + kc * 32 + kb))[1];
        }
        union { short8v v; __hip_bfloat162 h[4]; } au;
        au.h[0] = __float22bfloat162_rn(make_float2(x0.x, x0.y));
        au.h[1] = __float22bfloat162_rn(make_float2(x0.z, x0.w));
        au.h[2] = __float22bfloat162_rn(make_float2(x1.x, x1.y));
        au.h[3] = __float22bfloat162_rn(make_float2(x1.z, x1.w));
        #pragma unroll
        for (int f = 0; f < 8; ++f) {
            short8v b = *(const short8v*)(Wt + (size_t)(f * 16 + c16) * CH + kc * 32 + kb);
            acc[f] = __builtin_amdgcn_mfma_f32_16x16x32_bf16(au.v, b, acc[f], 0, 0, 0);
        }
    }

    #pragma unroll
    for (int r = 0; r < 4; ++r) {
        int row_l = w * 16 + kq * 4 + r;            // C/D: row=(lane>>4)*4+reg
        int grow  = row0 + row_l;
        float dv  = (grow < N) ? dinv[grow] : 0.f;
        #pragma unroll
        for (int f = 0; f < 8; ++f) {
            int col = f * 16 + c16;                 // C/D: col=lane&15
            unsigned bo = ((unsigned)((row_l * CH + col) * 2)) ^ ((unsigned)(row_l & 7) << 4);
            *(unsigned short*)((char*)xs + bo) = f2bf(acc[f][r] * dv);
        }
    }
    __syncthreads();
    #pragma unroll
    for (int i = 0; i < 4; ++i) {
        int g = i * 256 + t;            // 1024 granules of 16B
        int row_l = g >> 4;
        unsigned bo = ((unsigned)(g * 16)) ^ ((unsigned)(row_l & 7) << 4);
        uint4 v = *(const uint4*)((const char*)xs + bo);
        int row = row0 + row_l;
        if (row < N) ((uint4*)(xwb + (size_t)row * CH))[g & 15] = v;
    }
}

// ---------- 4. fused fine-sort + gather: one block per bucket, 8 waves ----------
#define ACC8(U) \
    acc[0] += __uint_as_float((U).x << 16); \
    acc[1] += __uint_as_float((U).x & 0xffff0000u); \
    acc[2] += __uint_as_float((U).y << 16); \
    acc[3] += __uint_as_float((U).y & 0xffff0000u); \
    acc[4] += __uint_as_float((U).z << 16); \
    acc[5] += __uint_as_float((U).z & 0xffff0000u); \
    acc[6] += __uint_as_float((U).w << 16); \
    acc[7] += __uint_as_float((U).w & 0xffff0000u);

__global__ __launch_bounds__(512) void k_gather(const int* __restrict__ bucket_cnt,
                                                const unsigned* __restrict__ packed,
                                                const unsigned short* __restrict__ xwb,
                                                const float* __restrict__ dinv,
                                                const float* __restrict__ bias,
                                                float* __restrict__ out, int N) {
    __shared__ int fh[128];            // per-node degree
    __shared__ int fs[128];            // inclusive scan
    __shared__ int fc[128];            // scatter cursor
    __shared__ unsigned spk[BKCAP];    // staged packed entries
    __shared__ int      elds[BKCAP];   // node-grouped src indices
    int b = blockIdx.x;
    int t = threadIdx.x;
    int cnt = min(bucket_cnt[b], BKCAP);
    const unsigned* pk = packed + ((size_t)b << CAPSH);

    if (t < 128) fh[t] = 0;
    __syncthreads();
    for (int i = t; i < cnt; i += 512) {        // stage + fine histogram
        unsigned p = pk[i];
        spk[i] = p;
        atomicAdd(&fh[(p >> 20) & 127], 1);
    }
    __syncthreads();
    if (t < 128) fs[t] = fh[t];
    __syncthreads();
    for (int off = 1; off < 128; off <<= 1) {   // Hillis-Steele inclusive scan
        int v = 0;
        if (t < 128 && t >= off) v = fs[t - off];
        __syncthreads();
        if (t < 128) fs[t] += v;
        __syncthreads();
    }
    if (t < 128) fc[t] = fs[t] - fh[t];
    __syncthreads();
    for (int i = t; i < cnt; i += 512) {        // LDS scatter by node
        unsigned p = spk[i];
        int f = (p >> 20) & 127;
        int pos = atomicAdd(&fc[f], 1);
        elds[pos] = (int)(p & 0xFFFFF);
    }
    __syncthreads();

    // gather: 8 waves x 16 nodes, R7 inner loop (1-deep pipeline, shfl unconditional)
    int wv = t >> 6, lane = t & 63;
    int q = lane >> 4, c16 = lane & 15;
    const uint4* xw4 = (const uint4*)xwb;
    for (int i = 0; i < 16; ++i) {
        int nl = wv * 16 + i;                   // wave-uniform
        int n  = (b << BSH) + nl;
        if (n >= N) break;
        int deg = fh[nl];
        int beg = fs[nl] - deg;
        float acc[8];
        #pragma unroll
        for (int k = 0; k < 8; ++k) acc[k] = 0.f;

        for (int p0 = 0; p0 < deg; p0 += 64) {
            int m = deg - p0; if (m > 64) m = 64;
            int myi = 0;
            if (lane < m) myi = elds[beg + p0 + lane];   // LDS batch read
            int jj = q;
            int a  = __shfl(myi, jj);                    // unconditional (R8 lesson)
            int s  = (jj < m) ? a : N;
            uint4 u = xw4[(size_t)s * 16 + c16];
            for (int j = 4; j < m; j += 4) {
                int jj2 = j + q;
                int ss  = __shfl(myi, jj2 & 63);         // unconditional
                int s2  = (jj2 < m) ? ss : N;
                uint4 u2 = xw4[(size_t)s2 * 16 + c16];
                ACC8(u);
                u = u2;
            }
            ACC8(u);
        }
        #pragma unroll
        for (int k = 0; k < 8; ++k) {
            acc[k] += __shfl_xor(acc[k], 16);
            acc[k] += __shfl_xor(acc[k], 32);
        }
        if (lane < 16) {
            float dn = dinv[n];
            uint4 u = xw4[(size_t)n * 16 + c16];         // self-loop (pre-scaled)
            ACC8(u);
            float4 b0 = ((const float4*)bias)[c16 * 2];
            float4 b1 = ((const float4*)bias)[c16 * 2 + 1];
            float4 o0, o1;
            o0.x = fmaxf(fmaf(acc[0], dn, b0.x), 0.f);
            o0.y = fmaxf(fmaf(acc[1], dn, b0.y), 0.f);
            o0.z = fmaxf(fmaf(acc[2], dn, b0.z), 0.f);
            o0.w = fmaxf(fmaf(acc[3], dn, b0.w), 0.f);
            o1.x = fmaxf(fmaf(acc[4], dn, b1.x), 0.f);
            o1.y = fmaxf(fmaf(acc[5], dn, b1.y), 0.f);
            o1.z = fmaxf(fmaf(acc[6], dn, b1.z), 0.f);
            o1.w = fmaxf(fmaf(acc[7], dn, b1.w), 0.f);
            ((float4*)(out + (size_t)n * CH))[c16 * 2]     = o0;
            ((float4*)(out + (size_t)n * CH))[c16 * 2 + 1] = o1;
        }
    }
}

extern "C" void kernel_launch(void* const* d_in, const int* in_sizes, int n_in,
                              void* d_out, int out_size, void* d_ws, size_t ws_size,
                              hipStream_t stream) {
    const float* x  = (const float*)d_in[0];
    const int*   ei = (const int*)d_in[1];
    const float* W  = (const float*)d_in[2];
    const float* b  = (const float*)d_in[3];

    int N = in_sizes[0] / CH;
    int E = in_sizes[1] / 2;
    const int* src = ei;
    const int* dst = ei + E;
    float* out = (float*)d_out;

    int nbuck = (N + (1 << BSH) - 1) >> BSH;     // 782
    size_t nslots = (size_t)nbuck << CAPSH;      // 3.2M

    // workspace layout (aligned to 256 B each)
    auto al = [](uintptr_t p) { return (p + 255) & ~(uintptr_t)255; };
    uintptr_t base = (uintptr_t)d_ws;
    unsigned short* xwb = (unsigned short*)base;          // (N+1)*CH bf16, row N = zeros
    int* bucket_cnt = (int*)(xwb + (size_t)(N + 1) * CH); // nbuck (right after zero row)
    uintptr_t p = al((uintptr_t)(bucket_cnt + nbuck));
    float* dinv     = (float*)p;               p = al(p + (size_t)N * 4);
    unsigned short* Wt = (unsigned short*)p;   p = al(p + (size_t)CH * CH * 2);
    unsigned* packed   = (unsigned*)p;

    int nbin = (E + CHUNK - 1) / CHUNK;          // 512 for E=1.6M

    // one memset: xwb zero row + bucket_cnt (contiguous)
    hipMemsetAsync(xwb + (size_t)N * CH, 0, (size_t)CH * 2 + (size_t)nbuck * 4, stream);
    k_bin   <<<nbin, 256, 0, stream>>>(src, dst, E, bucket_cnt, packed, W, Wt);
    k_deg   <<<nbuck, 256, 0, stream>>>(bucket_cnt, packed, dinv, N);
    k_gemm  <<<(N + 63) / 64, 256, 0, stream>>>(x, Wt, dinv, xwb, N);
    k_gather<<<nbuck, 512, 0, stream>>>(bucket_cnt, packed, xwb, dinv, b, out, N);
}